// Round 4
// baseline (111.563 us; speedup 1.0000x reference)
//
#include <hip/hip_runtime.h>
#include <math.h>

// Problem constants
#define NQ 10
#define DIM 1024          // 2^10
#define NPTS 64
#define DFEAT 10
#define NLAYERS 5
#define REGS 16           // DIM / 64 amplitudes per lane

#define IS2 0.70710678118654752440f

// ---------------------------------------------------------------------------
// Kernel 1: psi_i = U(x_i)|0> per data point (one wave/block).
// idx = (r<<6)|lane: bits 0..5 in lane (shfl_xor), bits 6..9 in reg index.
//
// R3 lesson: DS-pipe throughput at 1 wave/CU is the limiter (~35 cyc/op
// effective), so minimize cross-lane ops:
//  - fuse H,RZ,RY into one 2x2 complex gate M_q = RY*RZ*H per qubit/layer
//    (RZ phase is layer-invariant: x index collapses to x[9-q] every layer)
//  - layer 1's 1q gates on |0> give a PRODUCT STATE -> zero shuffles
//  - layer 5's ring diag is data-independent diagonal -> cancels in
//    |<psi_j|psi_i>|^2; then layer-5 RY is outermost data-independent
//    unitary -> also cancels. Layer 5 = RZ*H only (c=1,s=0 in M).
// Lane-shuffle stages: 60 -> 24 (DS ops 1920 -> 768).
//
// M = RY(t)*RZ(x)*H, with cxq=cos(x/2), sxq=sin(x/2), c=cos(t/2), s=sin(t/2),
// p=(c+s)/sqrt2, q=(c-s)/sqrt2:
//   m00=( q*cx, -p*sx)  m01=( p*cx, -q*sx)
//   m10=( p*cx,  q*sx)  m11=(-q*cx, -p*sx)
// Layer-1 product state: u_q = M_q|0> = (m00, m10).
// ---------------------------------------------------------------------------
__global__ __launch_bounds__(64) void state_kernel(
    const float* __restrict__ data,     // (64,10)
    const float* __restrict__ params,   // (5,2,10)
    float2* __restrict__ psi)           // (64,1024)
{
    const int i    = blockIdx.x;
    const int lane = threadIdx.x;

    // rz angle for qubit q is x[9-q] in every layer (all starts % 10 == 0)
    float cxq[NQ], sxq[NQ];
#pragma unroll
    for (int q = 0; q < NQ; ++q) {
        float h = 0.5f * data[i * DFEAT + (9 - q)];
        cxq[q] = __cosf(h);
        sxq[q] = __sinf(h);
    }

    float re[REGS], im[REGS];

    // ---- layer 1: product state (no shuffles) ----
    {
        const float* ry = params;   // layer 0 bp[0]
        float u0r[NQ], u0i[NQ], u1r[NQ], u1i[NQ];
#pragma unroll
        for (int q = 0; q < NQ; ++q) {
            float h = 0.5f * ry[q];
            float c = __cosf(h), s = __sinf(h);
            float p = (c + s) * IS2, qm = (c - s) * IS2;
            u0r[q] =  qm * cxq[q];  u0i[q] = -p  * sxq[q];   // m00
            u1r[q] =  p  * cxq[q];  u1i[q] =  qm * sxq[q];   // m10
        }
        // lane part: product over qubits 0..5
        float Lr = ((lane >> 0) & 1) ? u1r[0] : u0r[0];
        float Li = ((lane >> 0) & 1) ? u1i[0] : u0i[0];
#pragma unroll
        for (int q = 1; q < 6; ++q) {
            float fr = ((lane >> q) & 1) ? u1r[q] : u0r[q];
            float fi = ((lane >> q) & 1) ? u1i[q] : u0i[q];
            float nr = Lr * fr - Li * fi;
            float ni = Lr * fi + Li * fr;
            Lr = nr; Li = ni;
        }
        // reg part: product over qubits 6..9 (compile-time bit selects)
#pragma unroll
        for (int r = 0; r < REGS; ++r) {
            float Rr = (r & 1) ? u1r[6] : u0r[6];
            float Ri = (r & 1) ? u1i[6] : u0i[6];
#pragma unroll
            for (int q = 7; q < NQ; ++q) {
                const int b = (r >> (q - 6)) & 1;
                float fr = b ? u1r[q] : u0r[q];
                float fi = b ? u1i[q] : u0i[q];
                float nr = Rr * fr - Ri * fi;
                float ni = Rr * fi + Ri * fr;
                Rr = nr; Ri = ni;
            }
            re[r] = Lr * Rr - Li * Ri;
            im[r] = Lr * Ri + Li * Rr;
        }
    }

    // ---- ring diag for layer L (L = 0..3; layer 4's cancels) ----
    // phase = sum_n b_n * (b_{(n+1)%10} - 0.5) * rg[n]
#define RING_DIAG(LAYER)                                                      \
    {                                                                         \
        const float* rg = params + (LAYER) * 2 * NQ + NQ;                     \
        float lanep = 0.f;                                                    \
        _Pragma("unroll")                                                     \
        for (int n = 0; n < 5; ++n) {                                         \
            float t = (((lane >> (n + 1)) & 1) ? 0.5f : -0.5f) * rg[n];       \
            lanep += ((lane >> n) & 1) ? t : 0.f;                             \
        }                                                                     \
        const float t5 = ((lane >> 5) & 1) ? rg[5] : 0.f;                     \
        const float t9 = ((lane & 1) ? 0.5f : -0.5f) * rg[9];                 \
        _Pragma("unroll")                                                     \
        for (int r = 0; r < REGS; ++r) {                                      \
            float ph = lanep + ((r & 1) ? 0.5f : -0.5f) * t5;                 \
            if (r & 8) ph += t9;                                              \
            if (r & 1) ph += ((r & 2) ? 0.5f : -0.5f) * rg[6];                \
            if (r & 2) ph += ((r & 4) ? 0.5f : -0.5f) * rg[7];                \
            if (r & 4) ph += ((r & 8) ? 0.5f : -0.5f) * rg[8];                \
            float s = __sinf(ph), c = __cosf(ph);                             \
            float nr = re[r] * c - im[r] * s;                                 \
            float ni = re[r] * s + im[r] * c;                                 \
            re[r] = nr; im[r] = ni;                                           \
        }                                                                     \
    }

    RING_DIAG(0)

    // ---- layers 2..5: fused M stages (+ ring for layers 2..4) ----
#pragma unroll
    for (int L = 1; L < NLAYERS; ++L) {
        const float* ry = params + L * 2 * NQ;
        float mp[NQ], mq[NQ];
#pragma unroll
        for (int q = 0; q < NQ; ++q) {
            float c, s;
            if (L == NLAYERS - 1) { c = 1.f; s = 0.f; }   // layer 5: RZ*H only
            else { float h = 0.5f * ry[q]; c = __cosf(h); s = __sinf(h); }
            mp[q] = (c + s) * IS2;
            mq[q] = (c - s) * IS2;
        }

        // lane qubits 0..5: batched shuffle stage + fused 2x2 complex gate
#pragma unroll
        for (int q = 0; q < 6; ++q) {
            const float m00r =  mq[q] * cxq[q], m00i = -mp[q] * sxq[q];
            const float m01r =  mp[q] * cxq[q], m01i = -mq[q] * sxq[q];
            const float m10r =  m01r,           m10i =  mq[q] * sxq[q];
            const float m11r = -m00r,           m11i =  m00i;
            const int bit = (lane >> q) & 1;
            const float msr = bit ? m11r : m00r, msi = bit ? m11i : m00i;
            const float mpr = bit ? m10r : m01r, mpi = bit ? m10i : m01i;
            float pr[REGS], pi[REGS];
#pragma unroll
            for (int r = 0; r < REGS; ++r) {
                pr[r] = __shfl_xor(re[r], 1 << q, 64);
                pi[r] = __shfl_xor(im[r], 1 << q, 64);
            }
#pragma unroll
            for (int r = 0; r < REGS; ++r) {
                float nr = msr * re[r] - msi * im[r] + mpr * pr[r] - mpi * pi[r];
                float ni = msr * im[r] + msi * re[r] + mpr * pi[r] + mpi * pr[r];
                re[r] = nr; im[r] = ni;
            }
        }

        // reg qubits 6..9: pure VALU 2x2 complex gate
#pragma unroll
        for (int q = 6; q < NQ; ++q) {
            const int m = 1 << (q - 6);
            const float m00r =  mq[q] * cxq[q], m00i = -mp[q] * sxq[q];
            const float m01r =  mp[q] * cxq[q], m01i = -mq[q] * sxq[q];
            const float m10r =  m01r,           m10i =  mq[q] * sxq[q];
            const float m11r = -m00r,           m11i =  m00i;
#pragma unroll
            for (int r = 0; r < REGS; ++r) {
                if (!(r & m)) {
                    const int r1 = r | m;
                    float a0r = re[r], a0i = im[r], a1r = re[r1], a1i = im[r1];
                    re[r]  = m00r * a0r - m00i * a0i + m01r * a1r - m01i * a1i;
                    im[r]  = m00r * a0i + m00i * a0r + m01r * a1i + m01i * a1r;
                    re[r1] = m10r * a0r - m10i * a0i + m11r * a1r - m11i * a1i;
                    im[r1] = m10r * a0i + m10i * a0r + m11r * a1i + m11i * a1r;
                }
            }
        }

        if (L == 1) RING_DIAG(1)
        if (L == 2) RING_DIAG(2)
        if (L == 3) RING_DIAG(3)
        // layer 5 (L==4): ring cancels in |<psi_j|psi_i>|^2 — skipped
    }

    // write psi_i (coalesced float2)
    float2* out = psi + i * DIM;
#pragma unroll
    for (int r = 0; r < REGS; ++r)
        out[(r << 6) | lane] = make_float2(re[r], im[r]);
}

// ---------------------------------------------------------------------------
// Kernel 2: K[i][j] = |<psi_j | psi_i>|^2. Symmetric -> compute j >= i, write
// both. 256-thread blocks, one wave per pair. float4 loads.
// ---------------------------------------------------------------------------
__global__ __launch_bounds__(256) void gram_kernel(
    const float4* __restrict__ psi4,  // (64, 512) float4 view of psi
    float* __restrict__ Kbuf)         // (4096,)
{
    const int wave = threadIdx.x >> 6;
    const int lane = threadIdx.x & 63;
    const int p    = blockIdx.x * 4 + wave;   // 0..4095
    const int i    = p >> 6;
    const int j    = p & 63;
    if (j < i) return;                        // symmetry: partner wave writes us

    const float4* a = psi4 + i * (DIM / 2);
    const float4* b = psi4 + j * (DIM / 2);

    float zr = 0.f, zi = 0.f;   // <psi_j|psi_i> = sum conj(b)*a
#pragma unroll
    for (int r = 0; r < 8; ++r) {
        const int k = (r << 6) | lane;
        float4 av = a[k], bv = b[k];
        zr += bv.x * av.x + bv.y * av.y + bv.z * av.z + bv.w * av.w;
        zi += bv.x * av.y - bv.y * av.x + bv.z * av.w - bv.w * av.z;
    }
#pragma unroll
    for (int off = 32; off; off >>= 1) {
        zr += __shfl_xor(zr, off, 64);
        zi += __shfl_xor(zi, off, 64);
    }
    if (lane == 0) {
        const float k = zr * zr + zi * zi;
        Kbuf[p] = k;
        Kbuf[(j << 6) | i] = k;
    }
}

// ---------------------------------------------------------------------------
// Kernel 3: KTA = sum(lm*K) / sqrt(sum(K*K) * sum(lm*lm)). 4 waves + LDS.
// ---------------------------------------------------------------------------
__global__ __launch_bounds__(256) void reduce_kernel(
    const float* __restrict__ Kbuf,
    const float* __restrict__ labels,
    float* __restrict__ out)
{
    __shared__ float sm[3][4];
    const int tid  = threadIdx.x;
    const int lane = tid & 63;
    const int wave = tid >> 6;

    float slk = 0.f, skk = 0.f, sll = 0.f;
#pragma unroll
    for (int it = 0; it < (NPTS * NPTS) / 256; ++it) {
        const int p = it * 256 + tid;
        const float K  = Kbuf[p];
        const float lm = labels[p >> 6] * labels[p & 63];
        slk += lm * K;
        skk += K * K;
        sll += lm * lm;
    }
#pragma unroll
    for (int off = 32; off; off >>= 1) {
        slk += __shfl_xor(slk, off, 64);
        skk += __shfl_xor(skk, off, 64);
        sll += __shfl_xor(sll, off, 64);
    }
    if (lane == 0) { sm[0][wave] = slk; sm[1][wave] = skk; sm[2][wave] = sll; }
    __syncthreads();
    if (tid == 0) {
        float a = sm[0][0] + sm[0][1] + sm[0][2] + sm[0][3];
        float b = sm[1][0] + sm[1][1] + sm[1][2] + sm[1][3];
        float c = sm[2][0] + sm[2][1] + sm[2][2] + sm[2][3];
        out[0] = a / sqrtf(b * c);
    }
}

extern "C" void kernel_launch(void* const* d_in, const int* in_sizes, int n_in,
                              void* d_out, int out_size, void* d_ws, size_t ws_size,
                              hipStream_t stream) {
    const float* data   = (const float*)d_in[0];  // (64,10)
    const float* labels = (const float*)d_in[1];  // (64,)
    const float* params = (const float*)d_in[2];  // (5,2,10)
    float* out = (float*)d_out;

    // workspace layout: psi (64*1024 float2 = 512 KB) | Kbuf (4096 floats)
    float2* psi  = (float2*)d_ws;
    float*  Kbuf = (float*)((char*)d_ws + (size_t)NPTS * DIM * sizeof(float2));

    state_kernel <<<NPTS,             64, 0, stream>>>(data, params, psi);
    gram_kernel  <<<NPTS * NPTS / 4, 256, 0, stream>>>((const float4*)psi, Kbuf);
    reduce_kernel<<<1,               256, 0, stream>>>(Kbuf, labels, out);
}

// Round 5
// 75.824 us; speedup vs baseline: 1.4713x; 1.4713x over previous
//
#include <hip/hip_runtime.h>
#include <math.h>

// Problem constants
#define NQ 10
#define DIM 1024          // 2^10
#define NPTS 64
#define DFEAT 10
#define NLAYERS 5
#define SREGS 4           // amps per thread in state kernel (DIM / 256)

#define IS2 0.70710678118654752440f

// ---------------------------------------------------------------------------
// Kernel 1: psi_i = U(x_i)|0> per data point. 256 threads (4 waves)/block.
// Amplitude index idx = (r<<8)|(wv<<6)|lane:
//   bits 0..5 -> lane (shfl_xor), bits 6..7 -> wave (LDS exchange),
//   bits 8..9 -> register r (in-register butterfly).
//
// R4 lesson: the fully-unrolled 1-wave kernel was INSTRUCTION-FETCH bound
// (~60 KB straight-line code, FETCH_SIZE 529 KB ~= 8 XCDs x code size,
// VALUBusy <1%). Fix: small rolled loops (layer body fetched once, then L1I
// hits) + 4 waves/CU to hide remaining latency. Gate coefficients live in a
// small LDS table so rolled loops can index them at runtime without scratch.
//
// Fused 1q gate per (layer,qubit): M = RY(t)*RZ(x)*H, with cx=cos(x/2),
// sx=sin(x/2), c=cos(t/2), s=sin(t/2), p=(c+s)/sqrt2, q=(c-s)/sqrt2:
//   m00=( q*cx, -p*sx)  m01=( p*cx, -q*sx)
//   m10=( p*cx,  q*sx)  m11=(-q*cx, -p*sx)
// (so m10r=m01r, m10i=-m01i, m11r=-m00r, m11i=m00i -> store 4 floats.)
// x angle is x[9-q] every layer (all starts % 10 == 0).
// Layer 5: ring diag is data-independent -> cancels in |<psi_j|psi_i>|^2;
// then layer-5 RY is the outermost data-independent unitary -> also cancels
// (c=1,s=0). Both verified absmax==0 in R4.
// ---------------------------------------------------------------------------
__global__ __launch_bounds__(256) void state_kernel(
    const float* __restrict__ data,     // (64,10)
    const float* __restrict__ params,   // (5,2,10)
    float2* __restrict__ psi)           // (64,1024)
{
    const int i    = blockIdx.x;
    const int tid  = threadIdx.x;
    const int lane = tid & 63;
    const int wv   = tid >> 6;

    __shared__ float4 mc[NLAYERS][NQ];   // (m00r, m00i, m01r, m01i)
    __shared__ float2 xbuf[16][64];      // [wv*4+r][lane] exchange buffer

    // ---- precompute fused gate coefficients (50 threads, once) ----
    if (tid < NLAYERS * NQ) {
        const int L = tid / NQ, q = tid - L * NQ;
        const float xh = 0.5f * data[i * DFEAT + (9 - q)];
        const float cx = __cosf(xh), sx = __sinf(xh);
        float c = 1.f, s = 0.f;
        if (L != NLAYERS - 1) {
            const float th = 0.5f * params[L * 2 * NQ + q];
            c = __cosf(th); s = __sinf(th);
        }
        const float p = (c + s) * IS2, qm = (c - s) * IS2;
        mc[L][q] = make_float4(qm * cx, -p * sx, p * cx, -qm * sx);
    }
    __syncthreads();

    float re[SREGS], im[SREGS];
#pragma unroll
    for (int r = 0; r < SREGS; ++r) { re[r] = 0.f; im[r] = 0.f; }
    if (tid == 0) re[0] = 1.f;   // |0>

#pragma unroll 1
    for (int L = 0; L < NLAYERS; ++L) {

        // ---- qubits 0..5: cross-lane butterfly (rolled) ----
#pragma unroll 1
        for (int q = 0; q < 6; ++q) {
            const float4 m = mc[L][q];
            const int   b = (lane >> q) & 1;
            const float msr = b ? -m.x : m.x;   // m11r / m00r
            const float msi = m.y;              // m11i == m00i
            const float mpr = m.z;              // m10r == m01r
            const float mpi = b ? -m.w : m.w;   // m10i / m01i
            float pr[SREGS], pi[SREGS];
#pragma unroll
            for (int r = 0; r < SREGS; ++r) {
                pr[r] = __shfl_xor(re[r], 1 << q, 64);
                pi[r] = __shfl_xor(im[r], 1 << q, 64);
            }
#pragma unroll
            for (int r = 0; r < SREGS; ++r) {
                const float nr = msr * re[r] - msi * im[r] + mpr * pr[r] - mpi * pi[r];
                const float ni = msr * im[r] + msi * re[r] + mpr * pi[r] + mpi * pr[r];
                re[r] = nr; im[r] = ni;
            }
        }

        // ---- qubits 6..7: cross-wave via LDS (rolled) ----
#pragma unroll 1
        for (int q = 6; q < 8; ++q) {
            const float4 m = mc[L][q];
            const int   b = (wv >> (q - 6)) & 1;
            const float msr = b ? -m.x : m.x;
            const float msi = m.y;
            const float mpr = m.z;
            const float mpi = b ? -m.w : m.w;
#pragma unroll
            for (int r = 0; r < SREGS; ++r)
                xbuf[(wv << 2) | r][lane] = make_float2(re[r], im[r]);
            __syncthreads();
            const int pw = wv ^ (1 << (q - 6));
#pragma unroll
            for (int r = 0; r < SREGS; ++r) {
                const float2 p2 = xbuf[(pw << 2) | r][lane];
                const float nr = msr * re[r] - msi * im[r] + mpr * p2.x - mpi * p2.y;
                const float ni = msr * im[r] + msi * re[r] + mpr * p2.y + mpi * p2.x;
                re[r] = nr; im[r] = ni;
            }
            __syncthreads();
        }

        // ---- qubits 8..9: in-register butterfly (compile-time reg indices) ----
#pragma unroll
        for (int q = 8; q < 10; ++q) {
            const int mask = 1 << (q - 8);
            const float4 m = mc[L][q];
            const float m00r = m.x, m00i = m.y, m01r = m.z, m01i = m.w;
            const float m10r = m.z, m10i = -m.w, m11r = -m.x, m11i = m.y;
#pragma unroll
            for (int r = 0; r < SREGS; ++r) {
                if (!(r & mask)) {
                    const int r1 = r | mask;
                    const float a0r = re[r],  a0i = im[r];
                    const float a1r = re[r1], a1i = im[r1];
                    re[r]  = m00r * a0r - m00i * a0i + m01r * a1r - m01i * a1i;
                    im[r]  = m00r * a0i + m00i * a0r + m01r * a1i + m01i * a1r;
                    re[r1] = m10r * a0r - m10i * a0i + m11r * a1r - m11i * a1i;
                    im[r1] = m10r * a0i + m10i * a0r + m11r * a1i + m11i * a1r;
                }
            }
        }

        // ---- crz ring diagonal (skip layer 5: cancels in |<.|.>|^2) ----
        if (L < NLAYERS - 1) {
            const float* rg = params + L * 2 * NQ + NQ;
            float ph[SREGS] = {0.f, 0.f, 0.f, 0.f};
#pragma unroll 1
            for (int n = 0; n < NQ; ++n) {
                const int   nn = (n == 9) ? 0 : (n + 1);
                const float g  = rg[n];     // uniform -> s_load, K$-cached
#pragma unroll
                for (int r = 0; r < SREGS; ++r) {
                    const int idx = (r << 8) | (wv << 6) | lane;
                    const float t = (((idx >> nn) & 1) ? 0.5f : -0.5f) * g;
                    ph[r] += ((idx >> n) & 1) ? t : 0.f;
                }
            }
#pragma unroll
            for (int r = 0; r < SREGS; ++r) {
                const float s = __sinf(ph[r]), c = __cosf(ph[r]);
                const float nr = re[r] * c - im[r] * s;
                const float ni = re[r] * s + im[r] * c;
                re[r] = nr; im[r] = ni;
            }
        }
    }

    // write psi_i (coalesced float2)
    float2* out = psi + i * DIM;
#pragma unroll
    for (int r = 0; r < SREGS; ++r)
        out[(r << 8) | (wv << 6) | lane] = make_float2(re[r], im[r]);
}

// ---------------------------------------------------------------------------
// Kernel 2: K[i][j] = |<psi_j | psi_i>|^2. Symmetric -> compute j >= i, write
// both. 256-thread blocks, one wave per pair. float4 loads.
// ---------------------------------------------------------------------------
__global__ __launch_bounds__(256) void gram_kernel(
    const float4* __restrict__ psi4,  // (64, 512) float4 view of psi
    float* __restrict__ Kbuf)         // (4096,)
{
    const int wave = threadIdx.x >> 6;
    const int lane = threadIdx.x & 63;
    const int p    = blockIdx.x * 4 + wave;   // 0..4095
    const int i    = p >> 6;
    const int j    = p & 63;
    if (j < i) return;                        // symmetry: partner wave writes us

    const float4* a = psi4 + i * (DIM / 2);
    const float4* b = psi4 + j * (DIM / 2);

    float zr = 0.f, zi = 0.f;   // <psi_j|psi_i> = sum conj(b)*a
#pragma unroll
    for (int r = 0; r < 8; ++r) {
        const int k = (r << 6) | lane;
        float4 av = a[k], bv = b[k];
        zr += bv.x * av.x + bv.y * av.y + bv.z * av.z + bv.w * av.w;
        zi += bv.x * av.y - bv.y * av.x + bv.z * av.w - bv.w * av.z;
    }
#pragma unroll
    for (int off = 32; off; off >>= 1) {
        zr += __shfl_xor(zr, off, 64);
        zi += __shfl_xor(zi, off, 64);
    }
    if (lane == 0) {
        const float k = zr * zr + zi * zi;
        Kbuf[p] = k;
        Kbuf[(j << 6) | i] = k;
    }
}

// ---------------------------------------------------------------------------
// Kernel 3: KTA = sum(lm*K) / sqrt(sum(K*K) * sum(lm*lm)). 4 waves + LDS.
// ---------------------------------------------------------------------------
__global__ __launch_bounds__(256) void reduce_kernel(
    const float* __restrict__ Kbuf,
    const float* __restrict__ labels,
    float* __restrict__ out)
{
    __shared__ float sm[3][4];
    const int tid  = threadIdx.x;
    const int lane = tid & 63;
    const int wave = tid >> 6;

    float slk = 0.f, skk = 0.f, sll = 0.f;
#pragma unroll
    for (int it = 0; it < (NPTS * NPTS) / 256; ++it) {
        const int p = it * 256 + tid;
        const float K  = Kbuf[p];
        const float lm = labels[p >> 6] * labels[p & 63];
        slk += lm * K;
        skk += K * K;
        sll += lm * lm;
    }
#pragma unroll
    for (int off = 32; off; off >>= 1) {
        slk += __shfl_xor(slk, off, 64);
        skk += __shfl_xor(skk, off, 64);
        sll += __shfl_xor(sll, off, 64);
    }
    if (lane == 0) { sm[0][wave] = slk; sm[1][wave] = skk; sm[2][wave] = sll; }
    __syncthreads();
    if (tid == 0) {
        float a = sm[0][0] + sm[0][1] + sm[0][2] + sm[0][3];
        float b = sm[1][0] + sm[1][1] + sm[1][2] + sm[1][3];
        float c = sm[2][0] + sm[2][1] + sm[2][2] + sm[2][3];
        out[0] = a / sqrtf(b * c);
    }
}

extern "C" void kernel_launch(void* const* d_in, const int* in_sizes, int n_in,
                              void* d_out, int out_size, void* d_ws, size_t ws_size,
                              hipStream_t stream) {
    const float* data   = (const float*)d_in[0];  // (64,10)
    const float* labels = (const float*)d_in[1];  // (64,)
    const float* params = (const float*)d_in[2];  // (5,2,10)
    float* out = (float*)d_out;

    // workspace layout: psi (64*1024 float2 = 512 KB) | Kbuf (4096 floats)
    float2* psi  = (float2*)d_ws;
    float*  Kbuf = (float*)((char*)d_ws + (size_t)NPTS * DIM * sizeof(float2));

    state_kernel <<<NPTS,            256, 0, stream>>>(data, params, psi);
    gram_kernel  <<<NPTS * NPTS / 4, 256, 0, stream>>>((const float4*)psi, Kbuf);
    reduce_kernel<<<1,               256, 0, stream>>>(Kbuf, labels, out);
}